// Round 6
// baseline (29610.263 us; speedup 1.0000x reference)
//
#include <hip/hip_runtime.h>
#include <math.h>

#define T_STEPS 8192
#define HID     2048
#define IN_SZ   256
#define OUT_SZ  128
#define NBLK    64             // scan workgroups
#define NTHR    512            // 8 waves
#define RPB     32             // rows per workgroup = HID/NBLK
#define SCRUB   0xFFFFFFFF00000000ull

typedef unsigned long long u64;
typedef unsigned int u32;
typedef __attribute__((ext_vector_type(4))) u32 u32x4;

// ---------------------------------------------------------------------------
// ws layout: u64 ring[3][HID]. Entry = (tag<<32) | float_bits; slot t%3 holds
// r_t tagged t. Producers: fire-and-forget 8B agent-scope atomic stores
// (proven coherent R3). Consumers: two dwordx4 sc1 loads in one asm round
// trip; every 8B half carries its own tag (tear-proof). 32-round fast spin,
// then proven __hip_atomic_load fallback (deadlock-impossible).
// Skew between blocks <=1 step => depth-3 ring never aliases.
// R6: 64 blocks x 32 rows, Wh register-resident (128 VGPR/thread), LDS only
// for the 8KB r broadcast; lanes 0-3 of each wave own one row's epilogue.
// ---------------------------------------------------------------------------

__global__ void k_init(const float* __restrict__ rate, u64* ring) {
    int i = blockIdx.x * blockDim.x + threadIdx.x;
    if (i < HID) {
        ring[i] = (u64)__float_as_uint(rate[i]);   // tag 0 | r0 bits
        ring[HID + i]     = SCRUB;
        ring[2 * HID + i] = SCRUB;
    }
}

// ---------------------------------------------------------------------------
// xproj[h, t] = sum_i Wi[h,i] * sig[i,t] + bi[h]   -> written to out2 (H,T)
// ---------------------------------------------------------------------------
__global__ void __launch_bounds__(256) k_xproj(const float* __restrict__ sig,
                                               const float* __restrict__ Wi,
                                               const float* __restrict__ bi,
                                               float* __restrict__ out2) {
    __shared__ float wl[32 * IN_SZ];  // 32 KB
    const int tid = threadIdx.x;
    const int t0 = blockIdx.x * 512;
    const int h0 = blockIdx.y * 32;

    {
        const float4* s4 = (const float4*)(Wi + (size_t)h0 * IN_SZ);
        float4* d4 = (float4*)wl;
        #pragma unroll
        for (int k = 0; k < 8; ++k) d4[tid + k * 256] = s4[tid + k * 256];
    }
    __syncthreads();

    const int t1 = t0 + tid, t2 = t1 + 256;
    float acc1[32], acc2[32];
    #pragma unroll
    for (int j = 0; j < 32; ++j) { acc1[j] = 0.f; acc2[j] = 0.f; }

    for (int i = 0; i < IN_SZ; ++i) {
        float s1 = sig[(size_t)i * T_STEPS + t1];
        float s2 = sig[(size_t)i * T_STEPS + t2];
        #pragma unroll
        for (int j = 0; j < 32; ++j) {
            float w = wl[j * IN_SZ + i];
            acc1[j] = fmaf(w, s1, acc1[j]);
            acc2[j] = fmaf(w, s2, acc2[j]);
        }
    }
    #pragma unroll
    for (int j = 0; j < 32; ++j) {
        float b = bi[h0 + j];
        out2[(size_t)(h0 + j) * T_STEPS + t1] = acc1[j] + b;
        out2[(size_t)(h0 + j) * T_STEPS + t2] = acc2[j] + b;
    }
}

// ---------------------------------------------------------------------------
// Persistent scan. 64 blocks x 512 threads (cooperative). Block b owns rows
// h0 = b*32 .. +31; wave w (0..7) owns rows h0+4w .. +3, held in VGPRs.
// ---------------------------------------------------------------------------
__global__ void __launch_bounds__(512) k_scan(const float* __restrict__ Wh,
                                              const float* __restrict__ bh,
                                              float* __restrict__ out2,
                                              u64* ring) {
    __shared__ float rl[HID];         // 8 KB: the r_t broadcast buffer
    const int tid  = threadIdx.x;
    const int bid  = blockIdx.x;
    const int w    = tid >> 6;
    const int lane = tid & 63;
    const int h0   = bid * RPB;
    const int ra   = h0 + 4 * w;      // wave's first row

    // ---- Wh rows ra..ra+3 into registers: wr[j][c] = Wh4[row j][c*64+lane]
    float4 wr[4][8];
    {
        const float4* Wh4 = (const float4*)Wh;
        #pragma unroll
        for (int j = 0; j < 4; ++j)
            #pragma unroll
            for (int c = 0; c < 8; ++c)
                wr[j][c] = Wh4[(size_t)(ra + j) * (HID / 4) + c * 64 + lane];
    }
    // lane j<4 owns row ra+j's epilogue
    const int myrow = ra + lane;
    float mybh = 0.f;
    if (lane < 4) mybh = bh[myrow];
    __syncthreads();

    int cur = 0;  // t % 3
    for (int t = 0; t < T_STEPS; ++t) {
        // ---- prefetch xp for my row (hides under the poll) ----
        float xp = 0.f;
        size_t myidx = 0;
        if (lane < 4) {
            myidx = (size_t)myrow * T_STEPS + t;
            xp = out2[myidx];
        }

        // ---- acquire my 4 entries of slot cur (tag must == t) ----
        {
            const u64* src = ring + (size_t)cur * HID;
            const u64* p0p = src + 4 * tid;
            const u64* p1p = p0p + 2;
            const u32 tt = (u32)t;
            u32x4 a0, a1;
            float f0, f1, f2, f3;
            int got = 0;
            for (int rounds = 0; rounds < 32; ++rounds) {
                asm volatile("global_load_dwordx4 %0, %2, off sc1\n\t"
                             "global_load_dwordx4 %1, %3, off sc1\n\t"
                             "s_waitcnt vmcnt(0)"
                             : "=&v"(a0), "=&v"(a1)
                             : "v"(p0p), "v"(p1p)
                             : "memory");
                __builtin_amdgcn_sched_barrier(0);
                if (a0.y == tt && a0.w == tt && a1.y == tt && a1.w == tt) {
                    f0 = __uint_as_float(a0.x);
                    f1 = __uint_as_float(a0.z);
                    f2 = __uint_as_float(a1.x);
                    f3 = __uint_as_float(a1.z);
                    got = 1;
                    break;
                }
            }
            if (!got) {
                u64 vals[4];
                unsigned pend = 0xFu;
                while (pend) {
                    #pragma unroll
                    for (int q = 0; q < 4; ++q) {
                        if (pend & (1u << q))
                            vals[q] = __hip_atomic_load(&p0p[q], __ATOMIC_RELAXED,
                                                        __HIP_MEMORY_SCOPE_AGENT);
                    }
                    #pragma unroll
                    for (int q = 0; q < 4; ++q) {
                        if ((pend & (1u << q)) && (u32)(vals[q] >> 32) == tt)
                            pend &= ~(1u << q);
                    }
                }
                f0 = __uint_as_float((u32)vals[0]);
                f1 = __uint_as_float((u32)vals[1]);
                f2 = __uint_as_float((u32)vals[2]);
                f3 = __uint_as_float((u32)vals[3]);
            }
            float4 v; v.x = f0; v.y = f1; v.z = f2; v.w = f3;
            ((float4*)rl)[tid] = v;   // ds_write_b128
        }
        __syncthreads();

        // ---- 4 dot products per wave, Wh from registers ----
        float p0 = 0.f, p1 = 0.f, p2 = 0.f, p3 = 0.f;
        {
            const float4* r4 = (const float4*)rl;
            #pragma unroll
            for (int c = 0; c < 8; ++c) {
                float4 rv = r4[c * 64 + lane];
                p0 = fmaf(rv.x, wr[0][c].x, p0); p0 = fmaf(rv.y, wr[0][c].y, p0);
                p0 = fmaf(rv.z, wr[0][c].z, p0); p0 = fmaf(rv.w, wr[0][c].w, p0);
                p1 = fmaf(rv.x, wr[1][c].x, p1); p1 = fmaf(rv.y, wr[1][c].y, p1);
                p1 = fmaf(rv.z, wr[1][c].z, p1); p1 = fmaf(rv.w, wr[1][c].w, p1);
                p2 = fmaf(rv.x, wr[2][c].x, p2); p2 = fmaf(rv.y, wr[2][c].y, p2);
                p2 = fmaf(rv.z, wr[2][c].z, p2); p2 = fmaf(rv.w, wr[2][c].w, p2);
                p3 = fmaf(rv.x, wr[3][c].x, p3); p3 = fmaf(rv.y, wr[3][c].y, p3);
                p3 = fmaf(rv.z, wr[3][c].z, p3); p3 = fmaf(rv.w, wr[3][c].w, p3);
            }
        }
        #pragma unroll
        for (int off = 32; off >= 1; off >>= 1) {
            p0 += __shfl_xor(p0, off, 64);
            p1 += __shfl_xor(p1, off, 64);
            p2 += __shfl_xor(p2, off, 64);
            p3 += __shfl_xor(p3, off, 64);
        }

        const int nxt = (cur == 2) ? 0 : cur + 1;
        if (lane < 4) {
            // static selection of my row's partial (no runtime indexing)
            float myp = (lane & 2) ? ((lane & 1) ? p3 : p2)
                                   : ((lane & 1) ? p1 : p0);
            float rold = rl[myrow];
            float v = myp + xp + mybh;
            float rn = 0.9f * rold + 0.1f * tanhf(v);
            out2[myidx] = rn;                  // rate_all output (plain, cached)
            u64* dst = ring + (size_t)nxt * HID;
            const u64 tagbits = (u64)(u32)(t + 1) << 32;
            __hip_atomic_store(&dst[myrow], tagbits | __float_as_uint(rn),
                               __ATOMIC_RELAXED, __HIP_MEMORY_SCOPE_AGENT);
        }
        cur = nxt;
    }
}

// ---------------------------------------------------------------------------
// logits[t,o] = sum_h rates[t,h]*Wo[o,h] + bo[o]; out0[o,t] = logsoftmax_o.
// ---------------------------------------------------------------------------
__global__ void __launch_bounds__(512) k_logits(const float* __restrict__ out2,
                                                const float* __restrict__ Wo,
                                                const float* __restrict__ bo,
                                                float* __restrict__ out0) {
    __shared__ float wos[128 * 128];  // 64 KB
    __shared__ float red[8 * 128];    // 4 KB
    __shared__ float fin[128];
    const int tid  = threadIdx.x;
    const int w    = tid >> 6;
    const int lane = tid & 63;
    const int t0   = blockIdx.x * 128;
    const int ob   = w * 16;

    float acc0[16], acc1[16];
    #pragma unroll
    for (int j = 0; j < 16; ++j) { acc0[j] = 0.f; acc1[j] = 0.f; }

    for (int hb = 0; hb < HID / 128; ++hb) {
        __syncthreads();
        {
            const float4* wo4 = (const float4*)Wo;
            float4* ws4 = (float4*)wos;
            #pragma unroll
            for (int k = 0; k < 8; ++k) {
                int g = tid + k * 512;
                int o = g >> 5;
                int c = g & 31;
                ws4[g] = wo4[(size_t)o * (HID / 4) + hb * 32 + c];
            }
        }
        __syncthreads();
        for (int hh = 0; hh < 128; ++hh) {
            int h = hb * 128 + hh;
            float rA = out2[(size_t)h * T_STEPS + t0 + lane];
            float rB = out2[(size_t)h * T_STEPS + t0 + 64 + lane];
            #pragma unroll
            for (int j = 0; j < 16; ++j) {
                float wv = wos[(ob + j) * 128 + hh];
                acc0[j] = fmaf(wv, rA, acc0[j]);
                acc1[j] = fmaf(wv, rB, acc1[j]);
            }
        }
    }
    #pragma unroll
    for (int j = 0; j < 16; ++j) {
        float b = bo[ob + j];
        acc0[j] += b; acc1[j] += b;
    }

    float m0 = acc0[0], m1 = acc1[0];
    #pragma unroll
    for (int j = 1; j < 16; ++j) { m0 = fmaxf(m0, acc0[j]); m1 = fmaxf(m1, acc1[j]); }
    red[w * 128 + lane] = m0;
    red[w * 128 + 64 + lane] = m1;
    __syncthreads();
    if (tid < 128) {
        float m = red[tid];
        #pragma unroll
        for (int q = 1; q < 8; ++q) m = fmaxf(m, red[q * 128 + tid]);
        fin[tid] = m;
    }
    __syncthreads();
    float fm0 = fin[lane], fm1 = fin[64 + lane];
    float s0 = 0.f, s1 = 0.f;
    #pragma unroll
    for (int j = 0; j < 16; ++j) {
        s0 += expf(acc0[j] - fm0);
        s1 += expf(acc1[j] - fm1);
    }
    red[w * 128 + lane] = s0;
    red[w * 128 + 64 + lane] = s1;
    __syncthreads();
    if (tid < 128) {
        float s = 0.f;
        #pragma unroll
        for (int q = 0; q < 8; ++q) s += red[q * 128 + tid];
        fin[tid] = fin[tid] + logf(s);
    }
    __syncthreads();
    float L0 = fin[lane], L1 = fin[64 + lane];
    #pragma unroll
    for (int j = 0; j < 16; ++j) {
        out0[(size_t)(ob + j) * T_STEPS + t0 + lane]      = acc0[j] - L0;
        out0[(size_t)(ob + j) * T_STEPS + t0 + 64 + lane] = acc1[j] - L1;
    }
}

// ---------------------------------------------------------------------------
extern "C" void kernel_launch(void* const* d_in, const int* in_sizes, int n_in,
                              void* d_out, int out_size, void* d_ws, size_t ws_size,
                              hipStream_t stream) {
    const float* sig  = (const float*)d_in[0];
    const float* rate = (const float*)d_in[1];
    const float* Wi   = (const float*)d_in[2];
    const float* bi   = (const float*)d_in[3];
    const float* Wh   = (const float*)d_in[4];
    const float* bh   = (const float*)d_in[5];
    const float* Wo   = (const float*)d_in[6];
    const float* bo   = (const float*)d_in[7];

    float* out0 = (float*)d_out;                       // (128, 8192) logsoftmax
    float* out2 = out0 + (size_t)OUT_SZ * T_STEPS;     // (2048, 8192) rate_all

    u64* ring = (u64*)d_ws;                            // 3*HID u64 = 48 KB

    hipLaunchKernelGGL(k_init, dim3(8), dim3(256), 0, stream, rate, ring);
    hipLaunchKernelGGL(k_xproj, dim3(T_STEPS / 512, HID / 32), dim3(256), 0, stream,
                       sig, Wi, bi, out2);

    void* args[] = {(void*)&Wh, (void*)&bh, (void*)&out2, (void*)&ring};
    hipLaunchCooperativeKernel((const void*)k_scan, dim3(NBLK), dim3(NTHR),
                               args, 0, stream);

    hipLaunchKernelGGL(k_logits, dim3(T_STEPS / 128), dim3(512), 0, stream,
                       out2, Wo, bo, out0);
}

// Round 8
// 17722.252 us; speedup vs baseline: 1.6708x; 1.6708x over previous
//
#include <hip/hip_runtime.h>
#include <math.h>

#define T_STEPS 8192
#define HID     2048
#define IN_SZ   256
#define OUT_SZ  128
#define NBLK    64             // scan workgroups
#define NTHR    512            // 8 waves
#define RPB     32             // rows per workgroup = HID/NBLK
#define SCRUB   0xFFFFFFFF00000000ull

typedef unsigned long long u64;
typedef unsigned int u32;
typedef __attribute__((ext_vector_type(4))) u32 u32x4;

// ---------------------------------------------------------------------------
// ws layout: u64 ring[3][HID]. Entry = (tag<<32) | float_bits; slot t%3 holds
// r_t tagged t. Producers: fire-and-forget 8B agent-scope atomic stores
// (proven coherent R3). Consumers: two dwordx4 sc1 loads in one asm round
// trip; every 8B half carries its own tag (tear-proof). 32-round fast spin,
// then proven __hip_atomic_load fallback (deadlock-impossible).
// Skew between blocks <=1 step => depth-3 ring never aliases.
// R8: 64 blocks x 32 rows. Per wave: rows ra,ra+1 in LDS (128KB/block),
// rows ra+2,ra+3 in 64 NAMED SCALAR registers pinned with scalar "+v" asm
// (R7's float4-element pin didn't compile; R6 without a pin rematerialized
// the loads -> VGPR=88, FETCH +340MB/step).
// ---------------------------------------------------------------------------

__global__ void k_init(const float* __restrict__ rate, u64* ring) {
    int i = blockIdx.x * blockDim.x + threadIdx.x;
    if (i < HID) {
        ring[i] = (u64)__float_as_uint(rate[i]);   // tag 0 | r0 bits
        ring[HID + i]     = SCRUB;
        ring[2 * HID + i] = SCRUB;
    }
}

// ---------------------------------------------------------------------------
// xproj[h, t] = sum_i Wi[h,i] * sig[i,t] + bi[h]   -> written to out2 (H,T)
// ---------------------------------------------------------------------------
__global__ void __launch_bounds__(256) k_xproj(const float* __restrict__ sig,
                                               const float* __restrict__ Wi,
                                               const float* __restrict__ bi,
                                               float* __restrict__ out2) {
    __shared__ float wl[32 * IN_SZ];  // 32 KB
    const int tid = threadIdx.x;
    const int t0 = blockIdx.x * 512;
    const int h0 = blockIdx.y * 32;

    {
        const float4* s4 = (const float4*)(Wi + (size_t)h0 * IN_SZ);
        float4* d4 = (float4*)wl;
        #pragma unroll
        for (int k = 0; k < 8; ++k) d4[tid + k * 256] = s4[tid + k * 256];
    }
    __syncthreads();

    const int t1 = t0 + tid, t2 = t1 + 256;
    float acc1[32], acc2[32];
    #pragma unroll
    for (int j = 0; j < 32; ++j) { acc1[j] = 0.f; acc2[j] = 0.f; }

    for (int i = 0; i < IN_SZ; ++i) {
        float s1 = sig[(size_t)i * T_STEPS + t1];
        float s2 = sig[(size_t)i * T_STEPS + t2];
        #pragma unroll
        for (int j = 0; j < 32; ++j) {
            float w = wl[j * IN_SZ + i];
            acc1[j] = fmaf(w, s1, acc1[j]);
            acc2[j] = fmaf(w, s2, acc2[j]);
        }
    }
    #pragma unroll
    for (int j = 0; j < 32; ++j) {
        float b = bi[h0 + j];
        out2[(size_t)(h0 + j) * T_STEPS + t1] = acc1[j] + b;
        out2[(size_t)(h0 + j) * T_STEPS + t2] = acc2[j] + b;
    }
}

// ---- 64 named scalars for the two register-resident Wh rows ----
#define DECLROW(p) \
    float p##_0,  p##_1,  p##_2,  p##_3,  p##_4,  p##_5,  p##_6,  p##_7,  \
          p##_8,  p##_9,  p##_10, p##_11, p##_12, p##_13, p##_14, p##_15, \
          p##_16, p##_17, p##_18, p##_19, p##_20, p##_21, p##_22, p##_23, \
          p##_24, p##_25, p##_26, p##_27, p##_28, p##_29, p##_30, p##_31

#define SCAT(v, a, b, c, d) a = (v).x; b = (v).y; c = (v).z; d = (v).w

#define PIN8(a,b,c,d,e,f,g,h) \
    asm volatile("" : "+v"(a), "+v"(b), "+v"(c), "+v"(d), \
                      "+v"(e), "+v"(f), "+v"(g), "+v"(h))

#define PINROW(p) \
    PIN8(p##_0,  p##_1,  p##_2,  p##_3,  p##_4,  p##_5,  p##_6,  p##_7);  \
    PIN8(p##_8,  p##_9,  p##_10, p##_11, p##_12, p##_13, p##_14, p##_15); \
    PIN8(p##_16, p##_17, p##_18, p##_19, p##_20, p##_21, p##_22, p##_23); \
    PIN8(p##_24, p##_25, p##_26, p##_27, p##_28, p##_29, p##_30, p##_31)

#define DOTC(c, s0, s1, s2, s3) { \
    float4 rv = r4[(c) * 64 + lane]; \
    float4 av = a4[(c) * 64 + lane]; \
    float4 bv = b4[(c) * 64 + lane]; \
    p0 = fmaf(rv.x, av.x, p0); p0 = fmaf(rv.y, av.y, p0); \
    p0 = fmaf(rv.z, av.z, p0); p0 = fmaf(rv.w, av.w, p0); \
    p1 = fmaf(rv.x, bv.x, p1); p1 = fmaf(rv.y, bv.y, p1); \
    p1 = fmaf(rv.z, bv.z, p1); p1 = fmaf(rv.w, bv.w, p1); \
    p2 = fmaf(rv.x, wc_##s0, p2); p2 = fmaf(rv.y, wc_##s1, p2); \
    p2 = fmaf(rv.z, wc_##s2, p2); p2 = fmaf(rv.w, wc_##s3, p2); \
    p3 = fmaf(rv.x, wd_##s0, p3); p3 = fmaf(rv.y, wd_##s1, p3); \
    p3 = fmaf(rv.z, wd_##s2, p3); p3 = fmaf(rv.w, wd_##s3, p3); }

// ---------------------------------------------------------------------------
// Persistent scan. 64 blocks x 512 threads (cooperative). Block b owns rows
// h0 = b*32 .. +31; wave w (0..7) owns rows ra=h0+4w .. +3.
// Rows ra,ra+1 from LDS; rows ra+2,ra+3 from pinned scalar registers.
// ---------------------------------------------------------------------------
__global__ void __launch_bounds__(512, 2) k_scan(const float* __restrict__ Wh,
                                                 const float* __restrict__ bh,
                                                 float* __restrict__ out2,
                                                 u64* ring) {
    __shared__ float whs[16 * HID];   // 128 KB: wave w rows at 2w, 2w+1
    __shared__ float rl[HID];         // 8 KB: the r_t broadcast buffer
    const int tid  = threadIdx.x;
    const int bid  = blockIdx.x;
    const int w    = tid >> 6;
    const int lane = tid & 63;
    const int h0   = bid * RPB;
    const int ra   = h0 + 4 * w;      // wave's first row

    const float4* Wh4 = (const float4*)Wh;
    // ---- LDS rows: whs row rr <- Wh row h0 + 4*(rr>>1) + (rr&1)
    {
        float4* whs4 = (float4*)whs;
        #pragma unroll
        for (int rr = 0; rr < 16; ++rr) {
            int grow = h0 + 4 * (rr >> 1) + (rr & 1);
            whs4[rr * 512 + tid] = Wh4[(size_t)grow * 512 + tid];
        }
    }
    // ---- register rows ra+2 (wc), ra+3 (wd): 64 named scalars, pinned ----
    DECLROW(wc);
    DECLROW(wd);
    {
        const float4* rp = Wh4 + (size_t)(ra + 2) * 512;
        const float4* rq = Wh4 + (size_t)(ra + 3) * 512;
        float4 v;
        v = rp[0 * 64 + lane]; SCAT(v, wc_0,  wc_1,  wc_2,  wc_3);
        v = rp[1 * 64 + lane]; SCAT(v, wc_4,  wc_5,  wc_6,  wc_7);
        v = rp[2 * 64 + lane]; SCAT(v, wc_8,  wc_9,  wc_10, wc_11);
        v = rp[3 * 64 + lane]; SCAT(v, wc_12, wc_13, wc_14, wc_15);
        v = rp[4 * 64 + lane]; SCAT(v, wc_16, wc_17, wc_18, wc_19);
        v = rp[5 * 64 + lane]; SCAT(v, wc_20, wc_21, wc_22, wc_23);
        v = rp[6 * 64 + lane]; SCAT(v, wc_24, wc_25, wc_26, wc_27);
        v = rp[7 * 64 + lane]; SCAT(v, wc_28, wc_29, wc_30, wc_31);
        v = rq[0 * 64 + lane]; SCAT(v, wd_0,  wd_1,  wd_2,  wd_3);
        v = rq[1 * 64 + lane]; SCAT(v, wd_4,  wd_5,  wd_6,  wd_7);
        v = rq[2 * 64 + lane]; SCAT(v, wd_8,  wd_9,  wd_10, wd_11);
        v = rq[3 * 64 + lane]; SCAT(v, wd_12, wd_13, wd_14, wd_15);
        v = rq[4 * 64 + lane]; SCAT(v, wd_16, wd_17, wd_18, wd_19);
        v = rq[5 * 64 + lane]; SCAT(v, wd_20, wd_21, wd_22, wd_23);
        v = rq[6 * 64 + lane]; SCAT(v, wd_24, wd_25, wd_26, wd_27);
        v = rq[7 * 64 + lane]; SCAT(v, wd_28, wd_29, wd_30, wd_31);
    }
    PINROW(wc);
    PINROW(wd);

    // lane j<4 owns row ra+j's epilogue
    const int myrow = ra + lane;
    float mybh = 0.f;
    if (lane < 4) mybh = bh[myrow];
    __syncthreads();

    int cur = 0;  // t % 3
    for (int t = 0; t < T_STEPS; ++t) {
        // ---- prefetch xp for my row (hides under the poll) ----
        float xp = 0.f;
        size_t myidx = 0;
        if (lane < 4) {
            myidx = (size_t)myrow * T_STEPS + t;
            xp = out2[myidx];
        }

        // ---- acquire my 4 entries of slot cur (tag must == t) ----
        {
            const u64* src = ring + (size_t)cur * HID;
            const u64* p0p = src + 4 * tid;
            const u64* p1p = p0p + 2;
            const u32 tt = (u32)t;
            u32x4 a0, a1;
            float f0, f1, f2, f3;
            int got = 0;
            for (int rounds = 0; rounds < 32; ++rounds) {
                asm volatile("global_load_dwordx4 %0, %2, off sc1\n\t"
                             "global_load_dwordx4 %1, %3, off sc1\n\t"
                             "s_waitcnt vmcnt(0)"
                             : "=&v"(a0), "=&v"(a1)
                             : "v"(p0p), "v"(p1p)
                             : "memory");
                __builtin_amdgcn_sched_barrier(0);
                if (a0.y == tt && a0.w == tt && a1.y == tt && a1.w == tt) {
                    f0 = __uint_as_float(a0.x);
                    f1 = __uint_as_float(a0.z);
                    f2 = __uint_as_float(a1.x);
                    f3 = __uint_as_float(a1.z);
                    got = 1;
                    break;
                }
            }
            if (!got) {
                u64 vals[4];
                unsigned pend = 0xFu;
                while (pend) {
                    #pragma unroll
                    for (int q = 0; q < 4; ++q) {
                        if (pend & (1u << q))
                            vals[q] = __hip_atomic_load(&p0p[q], __ATOMIC_RELAXED,
                                                        __HIP_MEMORY_SCOPE_AGENT);
                    }
                    #pragma unroll
                    for (int q = 0; q < 4; ++q) {
                        if ((pend & (1u << q)) && (u32)(vals[q] >> 32) == tt)
                            pend &= ~(1u << q);
                    }
                }
                f0 = __uint_as_float((u32)vals[0]);
                f1 = __uint_as_float((u32)vals[1]);
                f2 = __uint_as_float((u32)vals[2]);
                f3 = __uint_as_float((u32)vals[3]);
            }
            float4 v; v.x = f0; v.y = f1; v.z = f2; v.w = f3;
            ((float4*)rl)[tid] = v;   // ds_write_b128
        }
        __syncthreads();

        // ---- 4 dot products per wave: 2 rows LDS + 2 rows registers ----
        float p0 = 0.f, p1 = 0.f, p2 = 0.f, p3 = 0.f;
        {
            const float4* r4 = (const float4*)rl;
            const float4* a4 = (const float4*)(whs + (size_t)(2 * w) * HID);
            const float4* b4 = a4 + 512;
            DOTC(0, 0,  1,  2,  3);
            DOTC(1, 4,  5,  6,  7);
            DOTC(2, 8,  9,  10, 11);
            DOTC(3, 12, 13, 14, 15);
            DOTC(4, 16, 17, 18, 19);
            DOTC(5, 20, 21, 22, 23);
            DOTC(6, 24, 25, 26, 27);
            DOTC(7, 28, 29, 30, 31);
        }
        #pragma unroll
        for (int off = 32; off >= 1; off >>= 1) {
            p0 += __shfl_xor(p0, off, 64);
            p1 += __shfl_xor(p1, off, 64);
            p2 += __shfl_xor(p2, off, 64);
            p3 += __shfl_xor(p3, off, 64);
        }

        const int nxt = (cur == 2) ? 0 : cur + 1;
        if (lane < 4) {
            // static selection of my row's partial (no runtime indexing)
            float myp = (lane & 2) ? ((lane & 1) ? p3 : p2)
                                   : ((lane & 1) ? p1 : p0);
            float rold = rl[myrow];
            float v = myp + xp + mybh;
            float rn = 0.9f * rold + 0.1f * tanhf(v);
            out2[myidx] = rn;                  // rate_all output (plain, cached)
            u64* dst = ring + (size_t)nxt * HID;
            const u64 tagbits = (u64)(u32)(t + 1) << 32;
            __hip_atomic_store(&dst[myrow], tagbits | __float_as_uint(rn),
                               __ATOMIC_RELAXED, __HIP_MEMORY_SCOPE_AGENT);
        }
        cur = nxt;
    }
}

// ---------------------------------------------------------------------------
// logits[t,o] = sum_h rates[t,h]*Wo[o,h] + bo[o]; out0[o,t] = logsoftmax_o.
// ---------------------------------------------------------------------------
__global__ void __launch_bounds__(512) k_logits(const float* __restrict__ out2,
                                                const float* __restrict__ Wo,
                                                const float* __restrict__ bo,
                                                float* __restrict__ out0) {
    __shared__ float wos[128 * 128];  // 64 KB
    __shared__ float red[8 * 128];    // 4 KB
    __shared__ float fin[128];
    const int tid  = threadIdx.x;
    const int w    = tid >> 6;
    const int lane = tid & 63;
    const int t0   = blockIdx.x * 128;
    const int ob   = w * 16;

    float acc0[16], acc1[16];
    #pragma unroll
    for (int j = 0; j < 16; ++j) { acc0[j] = 0.f; acc1[j] = 0.f; }

    for (int hb = 0; hb < HID / 128; ++hb) {
        __syncthreads();
        {
            const float4* wo4 = (const float4*)Wo;
            float4* ws4 = (float4*)wos;
            #pragma unroll
            for (int k = 0; k < 8; ++k) {
                int g = tid + k * 512;
                int o = g >> 5;
                int c = g & 31;
                ws4[g] = wo4[(size_t)o * (HID / 4) + hb * 32 + c];
            }
        }
        __syncthreads();
        for (int hh = 0; hh < 128; ++hh) {
            int h = hb * 128 + hh;
            float rA = out2[(size_t)h * T_STEPS + t0 + lane];
            float rB = out2[(size_t)h * T_STEPS + t0 + 64 + lane];
            #pragma unroll
            for (int j = 0; j < 16; ++j) {
                float wv = wos[(ob + j) * 128 + hh];
                acc0[j] = fmaf(wv, rA, acc0[j]);
                acc1[j] = fmaf(wv, rB, acc1[j]);
            }
        }
    }
    #pragma unroll
    for (int j = 0; j < 16; ++j) {
        float b = bo[ob + j];
        acc0[j] += b; acc1[j] += b;
    }

    float m0 = acc0[0], m1 = acc1[0];
    #pragma unroll
    for (int j = 1; j < 16; ++j) { m0 = fmaxf(m0, acc0[j]); m1 = fmaxf(m1, acc1[j]); }
    red[w * 128 + lane] = m0;
    red[w * 128 + 64 + lane] = m1;
    __syncthreads();
    if (tid < 128) {
        float m = red[tid];
        #pragma unroll
        for (int q = 1; q < 8; ++q) m = fmaxf(m, red[q * 128 + tid]);
        fin[tid] = m;
    }
    __syncthreads();
    float fm0 = fin[lane], fm1 = fin[64 + lane];
    float s0 = 0.f, s1 = 0.f;
    #pragma unroll
    for (int j = 0; j < 16; ++j) {
        s0 += expf(acc0[j] - fm0);
        s1 += expf(acc1[j] - fm1);
    }
    red[w * 128 + lane] = s0;
    red[w * 128 + 64 + lane] = s1;
    __syncthreads();
    if (tid < 128) {
        float s = 0.f;
        #pragma unroll
        for (int q = 0; q < 8; ++q) s += red[q * 128 + tid];
        fin[tid] = fin[tid] + logf(s);
    }
    __syncthreads();
    float L0 = fin[lane], L1 = fin[64 + lane];
    #pragma unroll
    for (int j = 0; j < 16; ++j) {
        out0[(size_t)(ob + j) * T_STEPS + t0 + lane]      = acc0[j] - L0;
        out0[(size_t)(ob + j) * T_STEPS + t0 + 64 + lane] = acc1[j] - L1;
    }
}

// ---------------------------------------------------------------------------
extern "C" void kernel_launch(void* const* d_in, const int* in_sizes, int n_in,
                              void* d_out, int out_size, void* d_ws, size_t ws_size,
                              hipStream_t stream) {
    const float* sig  = (const float*)d_in[0];
    const float* rate = (const float*)d_in[1];
    const float* Wi   = (const float*)d_in[2];
    const float* bi   = (const float*)d_in[3];
    const float* Wh   = (const float*)d_in[4];
    const float* bh   = (const float*)d_in[5];
    const float* Wo   = (const float*)d_in[6];
    const float* bo   = (const float*)d_in[7];

    float* out0 = (float*)d_out;                       // (128, 8192) logsoftmax
    float* out2 = out0 + (size_t)OUT_SZ * T_STEPS;     // (2048, 8192) rate_all

    u64* ring = (u64*)d_ws;                            // 3*HID u64 = 48 KB

    hipLaunchKernelGGL(k_init, dim3(8), dim3(256), 0, stream, rate, ring);
    hipLaunchKernelGGL(k_xproj, dim3(T_STEPS / 512, HID / 32), dim3(256), 0, stream,
                       sig, Wi, bi, out2);

    void* args[] = {(void*)&Wh, (void*)&bh, (void*)&out2, (void*)&ring};
    hipLaunchCooperativeKernel((const void*)k_scan, dim3(NBLK), dim3(NTHR),
                               args, 0, stream);

    hipLaunchKernelGGL(k_logits, dim3(T_STEPS / 128), dim3(512), 0, stream,
                       out2, Wo, bo, out0);
}

// Round 9
// 15193.077 us; speedup vs baseline: 1.9489x; 1.1665x over previous
//
#include <hip/hip_runtime.h>
#include <math.h>

#define T_STEPS 8192
#define HID     2048
#define IN_SZ   256
#define OUT_SZ  128
#define NBLK    128            // scan workgroups
#define NTHR    512            // 8 waves
#define RPB     16             // rows per workgroup = HID/NBLK
#define SCRUB   0xFFFFFFFF00000000ull

typedef unsigned long long u64;
typedef unsigned int u32;
typedef __attribute__((ext_vector_type(4))) u32 u32x4;

// ---------------------------------------------------------------------------
// ws layout: u64 ring[3][HID]. Entry = (tag<<32) | float_bits; slot t%3 holds
// r_t tagged t. Producers: fire-and-forget 8B agent-scope atomic stores
// (proven coherent R3). Consumers: two dwordx4 sc1 loads in one asm round
// trip; every 8B half carries its own tag (tear-proof). 32-round fast spin,
// then proven __hip_atomic_load fallback (deadlock-impossible).
// Skew between blocks <=1 step => depth-3 ring never aliases.
// R9: 128 blocks x 16 rows, but Wh is FULLY register-resident (2 rows/wave =
// 32 pinned scalars/thread; R8 proved the scalar pin sticks — values land in
// the unified AGPR file, no remat, no refetch). LDS per step = only the 8KB
// r broadcast -> 64KB/block/step of ds_read vs R5's 192KB (which at ~85B/cy
// was ~2260cy, half the step time).
// ---------------------------------------------------------------------------

__global__ void k_init(const float* __restrict__ rate, u64* ring) {
    int i = blockIdx.x * blockDim.x + threadIdx.x;
    if (i < HID) {
        ring[i] = (u64)__float_as_uint(rate[i]);   // tag 0 | r0 bits
        ring[HID + i]     = SCRUB;
        ring[2 * HID + i] = SCRUB;
    }
}

// ---------------------------------------------------------------------------
// xproj[h, t] = sum_i Wi[h,i] * sig[i,t] + bi[h]   -> written to out2 (H,T)
// ---------------------------------------------------------------------------
__global__ void __launch_bounds__(256) k_xproj(const float* __restrict__ sig,
                                               const float* __restrict__ Wi,
                                               const float* __restrict__ bi,
                                               float* __restrict__ out2) {
    __shared__ float wl[32 * IN_SZ];  // 32 KB
    const int tid = threadIdx.x;
    const int t0 = blockIdx.x * 512;
    const int h0 = blockIdx.y * 32;

    {
        const float4* s4 = (const float4*)(Wi + (size_t)h0 * IN_SZ);
        float4* d4 = (float4*)wl;
        #pragma unroll
        for (int k = 0; k < 8; ++k) d4[tid + k * 256] = s4[tid + k * 256];
    }
    __syncthreads();

    const int t1 = t0 + tid, t2 = t1 + 256;
    float acc1[32], acc2[32];
    #pragma unroll
    for (int j = 0; j < 32; ++j) { acc1[j] = 0.f; acc2[j] = 0.f; }

    for (int i = 0; i < IN_SZ; ++i) {
        float s1 = sig[(size_t)i * T_STEPS + t1];
        float s2 = sig[(size_t)i * T_STEPS + t2];
        #pragma unroll
        for (int j = 0; j < 32; ++j) {
            float w = wl[j * IN_SZ + i];
            acc1[j] = fmaf(w, s1, acc1[j]);
            acc2[j] = fmaf(w, s2, acc2[j]);
        }
    }
    #pragma unroll
    for (int j = 0; j < 32; ++j) {
        float b = bi[h0 + j];
        out2[(size_t)(h0 + j) * T_STEPS + t1] = acc1[j] + b;
        out2[(size_t)(h0 + j) * T_STEPS + t2] = acc2[j] + b;
    }
}

// ---- 32 named scalars per register-resident Wh row ----
#define DECLROW(p) \
    float p##_0,  p##_1,  p##_2,  p##_3,  p##_4,  p##_5,  p##_6,  p##_7,  \
          p##_8,  p##_9,  p##_10, p##_11, p##_12, p##_13, p##_14, p##_15, \
          p##_16, p##_17, p##_18, p##_19, p##_20, p##_21, p##_22, p##_23, \
          p##_24, p##_25, p##_26, p##_27, p##_28, p##_29, p##_30, p##_31

#define SCAT(v, a, b, c, d) a = (v).x; b = (v).y; c = (v).z; d = (v).w

#define PIN8(a,b,c,d,e,f,g,h) \
    asm volatile("" : "+v"(a), "+v"(b), "+v"(c), "+v"(d), \
                      "+v"(e), "+v"(f), "+v"(g), "+v"(h))

#define PINROW(p) \
    PIN8(p##_0,  p##_1,  p##_2,  p##_3,  p##_4,  p##_5,  p##_6,  p##_7);  \
    PIN8(p##_8,  p##_9,  p##_10, p##_11, p##_12, p##_13, p##_14, p##_15); \
    PIN8(p##_16, p##_17, p##_18, p##_19, p##_20, p##_21, p##_22, p##_23); \
    PIN8(p##_24, p##_25, p##_26, p##_27, p##_28, p##_29, p##_30, p##_31)

#define LOADROW(p, base) { \
    float4 v; \
    v = (base)[0 * 64 + lane]; SCAT(v, p##_0,  p##_1,  p##_2,  p##_3);  \
    v = (base)[1 * 64 + lane]; SCAT(v, p##_4,  p##_5,  p##_6,  p##_7);  \
    v = (base)[2 * 64 + lane]; SCAT(v, p##_8,  p##_9,  p##_10, p##_11); \
    v = (base)[3 * 64 + lane]; SCAT(v, p##_12, p##_13, p##_14, p##_15); \
    v = (base)[4 * 64 + lane]; SCAT(v, p##_16, p##_17, p##_18, p##_19); \
    v = (base)[5 * 64 + lane]; SCAT(v, p##_20, p##_21, p##_22, p##_23); \
    v = (base)[6 * 64 + lane]; SCAT(v, p##_24, p##_25, p##_26, p##_27); \
    v = (base)[7 * 64 + lane]; SCAT(v, p##_28, p##_29, p##_30, p##_31); }

#define DOTC(c, s0, s1, s2, s3) { \
    float4 rv = r4[(c) * 64 + lane]; \
    p0 = fmaf(rv.x, wa_##s0, p0); p0 = fmaf(rv.y, wa_##s1, p0); \
    p0 = fmaf(rv.z, wa_##s2, p0); p0 = fmaf(rv.w, wa_##s3, p0); \
    p1 = fmaf(rv.x, wb_##s0, p1); p1 = fmaf(rv.y, wb_##s1, p1); \
    p1 = fmaf(rv.z, wb_##s2, p1); p1 = fmaf(rv.w, wb_##s3, p1); }

// ---------------------------------------------------------------------------
// Persistent scan. 128 blocks x 512 threads (cooperative). Block b owns rows
// h0 = b*16 .. +15; wave w (0..7) owns rows ra=h0+2w, ra+1 in 64 pinned
// scalar registers. LDS holds only the r_t broadcast (8 KB).
// ---------------------------------------------------------------------------
__global__ void __launch_bounds__(512, 2) k_scan(const float* __restrict__ Wh,
                                                 const float* __restrict__ bh,
                                                 float* __restrict__ out2,
                                                 u64* ring) {
    __shared__ float rl[HID];         // 8 KB: the r_t broadcast buffer
    const int tid  = threadIdx.x;
    const int bid  = blockIdx.x;
    const int w    = tid >> 6;
    const int lane = tid & 63;
    const int h0   = bid * RPB;
    const int ra   = h0 + 2 * w;      // wave's first row

    const float4* Wh4 = (const float4*)Wh;
    // ---- register rows ra (wa), ra+1 (wb): 64 named scalars, pinned ----
    DECLROW(wa);
    DECLROW(wb);
    LOADROW(wa, Wh4 + (size_t)ra * 512);
    LOADROW(wb, Wh4 + (size_t)(ra + 1) * 512);
    PINROW(wa);
    PINROW(wb);

    // lane j<2 owns row ra+j's epilogue
    const int myrow = ra + lane;
    float mybh = 0.f;
    if (lane < 2) mybh = bh[myrow];
    __syncthreads();

    int cur = 0;  // t % 3
    for (int t = 0; t < T_STEPS; ++t) {
        // ---- prefetch xp for my row (hides under the poll) ----
        float xp = 0.f;
        size_t myidx = 0;
        if (lane < 2) {
            myidx = (size_t)myrow * T_STEPS + t;
            xp = out2[myidx];
        }

        // ---- acquire my 4 entries of slot cur (tag must == t) ----
        {
            const u64* src = ring + (size_t)cur * HID;
            const u64* p0p = src + 4 * tid;
            const u64* p1p = p0p + 2;
            const u32 tt = (u32)t;
            u32x4 a0, a1;
            float f0, f1, f2, f3;
            int got = 0;
            for (int rounds = 0; rounds < 32; ++rounds) {
                asm volatile("global_load_dwordx4 %0, %2, off sc1\n\t"
                             "global_load_dwordx4 %1, %3, off sc1\n\t"
                             "s_waitcnt vmcnt(0)"
                             : "=&v"(a0), "=&v"(a1)
                             : "v"(p0p), "v"(p1p)
                             : "memory");
                __builtin_amdgcn_sched_barrier(0);
                if (a0.y == tt && a0.w == tt && a1.y == tt && a1.w == tt) {
                    f0 = __uint_as_float(a0.x);
                    f1 = __uint_as_float(a0.z);
                    f2 = __uint_as_float(a1.x);
                    f3 = __uint_as_float(a1.z);
                    got = 1;
                    break;
                }
            }
            if (!got) {
                u64 vals[4];
                unsigned pend = 0xFu;
                while (pend) {
                    #pragma unroll
                    for (int q = 0; q < 4; ++q) {
                        if (pend & (1u << q))
                            vals[q] = __hip_atomic_load(&p0p[q], __ATOMIC_RELAXED,
                                                        __HIP_MEMORY_SCOPE_AGENT);
                    }
                    #pragma unroll
                    for (int q = 0; q < 4; ++q) {
                        if ((pend & (1u << q)) && (u32)(vals[q] >> 32) == tt)
                            pend &= ~(1u << q);
                    }
                }
                f0 = __uint_as_float((u32)vals[0]);
                f1 = __uint_as_float((u32)vals[1]);
                f2 = __uint_as_float((u32)vals[2]);
                f3 = __uint_as_float((u32)vals[3]);
            }
            float4 v; v.x = f0; v.y = f1; v.z = f2; v.w = f3;
            ((float4*)rl)[tid] = v;   // ds_write_b128
        }
        __syncthreads();

        // ---- 2 dot products per wave, Wh entirely from registers ----
        float p0 = 0.f, p1 = 0.f;
        {
            const float4* r4 = (const float4*)rl;
            DOTC(0, 0,  1,  2,  3);
            DOTC(1, 4,  5,  6,  7);
            DOTC(2, 8,  9,  10, 11);
            DOTC(3, 12, 13, 14, 15);
            DOTC(4, 16, 17, 18, 19);
            DOTC(5, 20, 21, 22, 23);
            DOTC(6, 24, 25, 26, 27);
            DOTC(7, 28, 29, 30, 31);
        }
        #pragma unroll
        for (int off = 32; off >= 1; off >>= 1) {
            p0 += __shfl_xor(p0, off, 64);
            p1 += __shfl_xor(p1, off, 64);
        }

        const int nxt = (cur == 2) ? 0 : cur + 1;
        if (lane < 2) {
            float myp = (lane & 1) ? p1 : p0;
            float rold = rl[myrow];
            float v = myp + xp + mybh;
            float rn = 0.9f * rold + 0.1f * tanhf(v);
            out2[myidx] = rn;                  // rate_all output (plain, cached)
            u64* dst = ring + (size_t)nxt * HID;
            const u64 tagbits = (u64)(u32)(t + 1) << 32;
            __hip_atomic_store(&dst[myrow], tagbits | __float_as_uint(rn),
                               __ATOMIC_RELAXED, __HIP_MEMORY_SCOPE_AGENT);
        }
        cur = nxt;
    }
}

// ---------------------------------------------------------------------------
// logits[t,o] = sum_h rates[t,h]*Wo[o,h] + bo[o]; out0[o,t] = logsoftmax_o.
// ---------------------------------------------------------------------------
__global__ void __launch_bounds__(512) k_logits(const float* __restrict__ out2,
                                                const float* __restrict__ Wo,
                                                const float* __restrict__ bo,
                                                float* __restrict__ out0) {
    __shared__ float wos[128 * 128];  // 64 KB
    __shared__ float red[8 * 128];    // 4 KB
    __shared__ float fin[128];
    const int tid  = threadIdx.x;
    const int w    = tid >> 6;
    const int lane = tid & 63;
    const int t0   = blockIdx.x * 128;
    const int ob   = w * 16;

    float acc0[16], acc1[16];
    #pragma unroll
    for (int j = 0; j < 16; ++j) { acc0[j] = 0.f; acc1[j] = 0.f; }

    for (int hb = 0; hb < HID / 128; ++hb) {
        __syncthreads();
        {
            const float4* wo4 = (const float4*)Wo;
            float4* ws4 = (float4*)wos;
            #pragma unroll
            for (int k = 0; k < 8; ++k) {
                int g = tid + k * 512;
                int o = g >> 5;
                int c = g & 31;
                ws4[g] = wo4[(size_t)o * (HID / 4) + hb * 32 + c];
            }
        }
        __syncthreads();
        for (int hh = 0; hh < 128; ++hh) {
            int h = hb * 128 + hh;
            float rA = out2[(size_t)h * T_STEPS + t0 + lane];
            float rB = out2[(size_t)h * T_STEPS + t0 + 64 + lane];
            #pragma unroll
            for (int j = 0; j < 16; ++j) {
                float wv = wos[(ob + j) * 128 + hh];
                acc0[j] = fmaf(wv, rA, acc0[j]);
                acc1[j] = fmaf(wv, rB, acc1[j]);
            }
        }
    }
    #pragma unroll
    for (int j = 0; j < 16; ++j) {
        float b = bo[ob + j];
        acc0[j] += b; acc1[j] += b;
    }

    float m0 = acc0[0], m1 = acc1[0];
    #pragma unroll
    for (int j = 1; j < 16; ++j) { m0 = fmaxf(m0, acc0[j]); m1 = fmaxf(m1, acc1[j]); }
    red[w * 128 + lane] = m0;
    red[w * 128 + 64 + lane] = m1;
    __syncthreads();
    if (tid < 128) {
        float m = red[tid];
        #pragma unroll
        for (int q = 1; q < 8; ++q) m = fmaxf(m, red[q * 128 + tid]);
        fin[tid] = m;
    }
    __syncthreads();
    float fm0 = fin[lane], fm1 = fin[64 + lane];
    float s0 = 0.f, s1 = 0.f;
    #pragma unroll
    for (int j = 0; j < 16; ++j) {
        s0 += expf(acc0[j] - fm0);
        s1 += expf(acc1[j] - fm1);
    }
    red[w * 128 + lane] = s0;
    red[w * 128 + 64 + lane] = s1;
    __syncthreads();
    if (tid < 128) {
        float s = 0.f;
        #pragma unroll
        for (int q = 0; q < 8; ++q) s += red[q * 128 + tid];
        fin[tid] = fin[tid] + logf(s);
    }
    __syncthreads();
    float L0 = fin[lane], L1 = fin[64 + lane];
    #pragma unroll
    for (int j = 0; j < 16; ++j) {
        out0[(size_t)(ob + j) * T_STEPS + t0 + lane]      = acc0[j] - L0;
        out0[(size_t)(ob + j) * T_STEPS + t0 + 64 + lane] = acc1[j] - L1;
    }
}

// ---------------------------------------------------------------------------
extern "C" void kernel_launch(void* const* d_in, const int* in_sizes, int n_in,
                              void* d_out, int out_size, void* d_ws, size_t ws_size,
                              hipStream_t stream) {
    const float* sig  = (const float*)d_in[0];
    const float* rate = (const float*)d_in[1];
    const float* Wi   = (const float*)d_in[2];
    const float* bi   = (const float*)d_in[3];
    const float* Wh   = (const float*)d_in[4];
    const float* bh   = (const float*)d_in[5];
    const float* Wo   = (const float*)d_in[6];
    const float* bo   = (const float*)d_in[7];

    float* out0 = (float*)d_out;                       // (128, 8192) logsoftmax
    float* out2 = out0 + (size_t)OUT_SZ * T_STEPS;     // (2048, 8192) rate_all

    u64* ring = (u64*)d_ws;                            // 3*HID u64 = 48 KB

    hipLaunchKernelGGL(k_init, dim3(8), dim3(256), 0, stream, rate, ring);
    hipLaunchKernelGGL(k_xproj, dim3(T_STEPS / 512, HID / 32), dim3(256), 0, stream,
                       sig, Wi, bi, out2);

    void* args[] = {(void*)&Wh, (void*)&bh, (void*)&out2, (void*)&ring};
    hipLaunchCooperativeKernel((const void*)k_scan, dim3(NBLK), dim3(NTHR),
                               args, 0, stream);

    hipLaunchKernelGGL(k_logits, dim3(T_STEPS / 128), dim3(512), 0, stream,
                       out2, Wo, bo, out0);
}